// Round 1
// baseline (701.529 us; speedup 1.0000x reference)
//
#include <hip/hip_runtime.h>

// Painting: sequentially alpha-composite N RGBA layers onto a white canvas.
//   canvas = canvas*(1 - a) + a*poly,  a = poly[:,3]*0.8  (broadcast over RGBA)
// polys layout: (N, 1, 4, H, W) fp32 row-major. Output: (1, 4, H, W) fp32.
//
// Key insight: each layer is an affine map c -> (1-a)*c + a*p, and affine maps
// compose associatively. The old single-pass kernel had only PHW4=65536 threads
// (1 wave/SIMD, 12.5% occupancy) and ran at ~815 GB/s (13% of HBM). We chunk
// the N dimension: pass 1 computes per-chunk (M, B) with CHUNKS x more threads
// (full occupancy), pass 2 combines the (mostly L3-resident) chunk results.

#define PH 512
#define PW 512
#define PHW (PH * PW)
#define PHW4 (PHW / 4)          // float4 groups per plane (65536)
#define OPACITY 0.8f

__device__ __forceinline__ void composite(float4& c, const float4& p, const float4& a) {
    // c = c*(1-a) + a*p  ==  c + a*(p - c)
    c.x = fmaf(a.x, p.x - c.x, c.x);
    c.y = fmaf(a.y, p.y - c.y, c.y);
    c.z = fmaf(a.z, p.z - c.z, c.z);
    c.w = fmaf(a.w, p.w - c.w, c.w);
}

// Pass 1: for chunk k covering layers [n0,n1), compute per-pixel affine
// (M, B) such that canvas_out = M*canvas_in + B.
//   M *= (1-a);  B = B + a*(p - B)   (B starts at 0, M at 1)
// Workspace layout per chunk: 5 planes of PHW4 float4: [M, B_r, B_g, B_b, B_a].
__global__ __launch_bounds__(256) void paint_chunk(const float4* __restrict__ polys,
                                                   float4* __restrict__ ws,
                                                   int n_polys, int n_chunks) {
    const int idx = blockIdx.x * blockDim.x + threadIdx.x;   // 0 .. PHW4-1
    const int chunk = blockIdx.y;
    const int n0 = (int)(((long long)chunk * n_polys) / n_chunks);
    const int n1 = (int)(((long long)(chunk + 1) * n_polys) / n_chunks);

    float4 m = make_float4(1.f, 1.f, 1.f, 1.f);
    float4 b0 = make_float4(0.f, 0.f, 0.f, 0.f);
    float4 b1 = b0, b2 = b0, b3 = b0;

    const float4* p = polys + (size_t)n0 * 4 * PHW4 + idx;
    #pragma unroll 4
    for (int n = n0; n < n1; ++n) {
        // 4 coalesced 16B loads: R,G,B,A planes of layer n
        const float4 p0 = p[0 * PHW4];
        const float4 p1 = p[1 * PHW4];
        const float4 p2 = p[2 * PHW4];
        const float4 p3 = p[3 * PHW4];
        p += 4 * PHW4;

        const float4 a = make_float4(p3.x * OPACITY, p3.y * OPACITY,
                                     p3.z * OPACITY, p3.w * OPACITY);
        composite(b0, p0, a);
        composite(b1, p1, a);
        composite(b2, p2, a);
        composite(b3, p3, a);
        m.x *= 1.f - a.x;
        m.y *= 1.f - a.y;
        m.z *= 1.f - a.z;
        m.w *= 1.f - a.w;
    }

    float4* w = ws + (size_t)chunk * 5 * PHW4 + idx;
    w[0 * PHW4] = m;
    w[1 * PHW4] = b0;
    w[2 * PHW4] = b1;
    w[3 * PHW4] = b2;
    w[4 * PHW4] = b3;
}

// Pass 2: canvas = 1; for k ascending: canvas = M_k*canvas + B_k.
// One channel per blockIdx.y (4x threads vs pixel groups for occupancy);
// M is re-read per channel but the workspace is freshly written -> L2/L3 hit.
__global__ __launch_bounds__(256) void combine_chunks(const float4* __restrict__ ws,
                                                      float4* __restrict__ out,
                                                      int n_chunks) {
    const int idx = blockIdx.x * blockDim.x + threadIdx.x;   // 0 .. PHW4-1
    const int ch = blockIdx.y;                                // 0..3
    float4 c = make_float4(1.f, 1.f, 1.f, 1.f);
    const float4* w = ws + idx;
    #pragma unroll 4
    for (int k = 0; k < n_chunks; ++k) {
        const float4 mm = w[0 * PHW4];
        const float4 bb = w[(1 + ch) * PHW4];
        c.x = fmaf(mm.x, c.x, bb.x);
        c.y = fmaf(mm.y, c.y, bb.y);
        c.z = fmaf(mm.z, c.z, bb.z);
        c.w = fmaf(mm.w, c.w, bb.w);
        w += 5 * PHW4;
    }
    out[(size_t)ch * PHW4 + idx] = c;
}

// Fallback: original single-pass kernel (used only if workspace is too small).
__global__ __launch_bounds__(256) void paint_kernel(const float4* __restrict__ polys,
                                                    float4* __restrict__ out,
                                                    int n_polys) {
    const int idx = blockIdx.x * blockDim.x + threadIdx.x;
    if (idx >= PHW4) return;

    const float4 one = make_float4(1.f, 1.f, 1.f, 1.f);
    float4 c0 = one, c1 = one, c2 = one, c3 = one;

    const float4* p = polys + idx;
    #pragma unroll 4
    for (int n = 0; n < n_polys; ++n) {
        const float4 p0 = p[0 * PHW4];
        const float4 p1 = p[1 * PHW4];
        const float4 p2 = p[2 * PHW4];
        const float4 p3 = p[3 * PHW4];
        p += 4 * PHW4;

        const float4 a = make_float4(p3.x * OPACITY, p3.y * OPACITY,
                                     p3.z * OPACITY, p3.w * OPACITY);
        composite(c0, p0, a);
        composite(c1, p1, a);
        composite(c2, p2, a);
        composite(c3, p3, a);
    }

    out[0 * PHW4 + idx] = c0;
    out[1 * PHW4 + idx] = c1;
    out[2 * PHW4 + idx] = c2;
    out[3 * PHW4 + idx] = c3;
}

extern "C" void kernel_launch(void* const* d_in, const int* in_sizes, int n_in,
                              void* d_out, int out_size, void* d_ws, size_t ws_size,
                              hipStream_t stream) {
    const float* polys = (const float*)d_in[0];
    float* out = (float*)d_out;

    // N derived from flat input element count; H=W=512 fixed by the reference.
    const int n_polys = in_sizes[0] / (4 * PHW);

    const size_t bytes_per_chunk = (size_t)5 * PHW4 * sizeof(float4);  // 5 MiB

    int n_chunks = 16;
    while (n_chunks > 1 && n_chunks > n_polys) n_chunks >>= 1;
    while (n_chunks > 1 && (size_t)n_chunks * bytes_per_chunk > ws_size) n_chunks >>= 1;

    const int threads = 256;
    if (d_ws == nullptr || n_chunks < 2 ||
        (size_t)n_chunks * bytes_per_chunk > ws_size) {
        // Workspace too small: original single-pass path.
        const int blocks = (PHW4 + threads - 1) / threads;
        paint_kernel<<<blocks, threads, 0, stream>>>((const float4*)polys,
                                                     (float4*)out, n_polys);
        return;
    }

    float4* ws = (float4*)d_ws;
    dim3 g1(PHW4 / threads, n_chunks);   // (256, 16): 32 waves/CU, full occupancy
    paint_chunk<<<g1, threads, 0, stream>>>((const float4*)polys, ws,
                                            n_polys, n_chunks);
    dim3 g2(PHW4 / threads, 4);          // (256, 4): one channel per y-row
    combine_chunks<<<g2, threads, 0, stream>>>(ws, (float4*)out, n_chunks);
}

// Round 2
// 674.396 us; speedup vs baseline: 1.0402x; 1.0402x over previous
//
#include <hip/hip_runtime.h>

// Painting: sequentially alpha-composite N RGBA layers onto a white canvas.
//   canvas = canvas*(1 - a) + a*poly,  a = poly[:,3]*0.8  (broadcast over RGBA)
// polys layout: (N, 1, 4, H, W) fp32 row-major. Output: (1, 4, H, W) fp32.
//
// Round-0 kernel (thread owns all 4 channels of 4 pixels) had only 65536
// threads = 1 wave/SIMD (12.5% occupancy) -> serial FMA chain + exposed
// s_waitcnt, ~810 GB/s (13% of HBM). Round-1 workspace-chunked scan collided
// with the harness's per-iteration 2-GiB workspace poison fills.
//
// This version: channel-split, NO workspace. Each wave owns ONE channel
// plane (wave id within block = channel), thread owns one float4 of that
// plane. 4x the threads: 262144 = 16 waves/CU (4/SIMD). The alpha plane is
// loaded by all 4 channel-waves of a block, but those are co-resident and
// co-scheduled -> L1/L2 hits, no extra HBM traffic. 2 loads/iter/thread,
// unroll 4 -> 8 loads in flight per wave.

#define PH 512
#define PW 512
#define PHW (PH * PW)
#define PHW4 (PHW / 4)          // float4 groups per plane (65536)
#define OPACITY 0.8f

__global__ __launch_bounds__(256) void paint_kernel(const float4* __restrict__ polys,
                                                    float4* __restrict__ out,
                                                    int n_polys) {
    // Block = 256 threads = 4 waves. Wave w (= threadIdx.x>>6) owns channel w.
    // Lane l covers pixel-group blockIdx.x*64 + l -> coalesced 1-KiB wave loads.
    const int tid   = threadIdx.x;
    const int ch    = tid >> 6;                       // 0..3, wave-uniform
    const int group = blockIdx.x * 64 + (tid & 63);   // 0 .. PHW4-1

    float4 c = make_float4(1.f, 1.f, 1.f, 1.f);

    const float4* pm = polys + (size_t)ch * PHW4 + group;  // my channel plane
    const float4* pa = polys + (size_t)3  * PHW4 + group;  // alpha plane
    const bool is_alpha = (ch == 3);                       // wave-uniform

    #pragma unroll 4
    for (int n = 0; n < n_polys; ++n) {
        const float4 p = pm[0];
        float4 al;
        if (is_alpha) {
            al = p;            // wave-uniform branch: alpha wave skips 2nd load
        } else {
            al = pa[0];        // same line as sibling waves' loads -> L1/L2 hit
        }
        pm += 4 * PHW4;
        pa += 4 * PHW4;

        // c = c*(1-a) + a*p  ==  c + a*(p - c),  a = al*0.8
        const float ax = al.x * OPACITY;
        const float ay = al.y * OPACITY;
        const float az = al.z * OPACITY;
        const float aw = al.w * OPACITY;
        c.x = fmaf(ax, p.x - c.x, c.x);
        c.y = fmaf(ay, p.y - c.y, c.y);
        c.z = fmaf(az, p.z - c.z, c.z);
        c.w = fmaf(aw, p.w - c.w, c.w);
    }

    out[(size_t)ch * PHW4 + group] = c;
}

extern "C" void kernel_launch(void* const* d_in, const int* in_sizes, int n_in,
                              void* d_out, int out_size, void* d_ws, size_t ws_size,
                              hipStream_t stream) {
    const float* polys = (const float*)d_in[0];
    float* out = (float*)d_out;

    // N derived from flat input element count; H=W=512 fixed by the reference.
    const int n_polys = in_sizes[0] / (4 * PHW);

    const int threads = 256;
    const int blocks = PHW4 / 64;   // 1024 blocks: 4 channel-waves x 64 groups each
    paint_kernel<<<blocks, threads, 0, stream>>>((const float4*)polys,
                                                 (float4*)out, n_polys);
}